// Round 1
// baseline (674.720 us; speedup 1.0000x reference)
//
#include <hip/hip_runtime.h>
#include <hip/hip_bf16.h>
#include <cstdint>
#include <cstddef>

typedef unsigned short u16;
typedef unsigned int u32;
typedef __attribute__((ext_vector_type(8))) short short8;
typedef __attribute__((ext_vector_type(4))) float floatx4;

#define DD 1024
#define NE 8

// 16-byte async global->LDS copy (gfx950). LDS dest must be wave-uniform base + lane*16.
#define GLOAD_LDS16(G, L)                                               \
  __builtin_amdgcn_global_load_lds(                                     \
      (const __attribute__((address_space(1))) void*)(G),               \
      (__attribute__((address_space(3))) void*)(L), 16, 0, 0)

__device__ __forceinline__ u16 f2bf(float f) {
  union { __hip_bfloat16 h; u16 u; } cv;
  cv.h = __float2bfloat16(f);
  return cv.u;
}

__device__ __forceinline__ u32 pk2(float a, float b) {
  float2 t; t.x = a; t.y = b;
  union { __hip_bfloat162 h2; u32 u; } cv;
  cv.h2 = __float22bfloat162_rn(t);
  return cv.u;
}

// ---------------- router: fp32 logits, top-2, softmax weights ----------------
__global__ __launch_bounds__(256) void router_kernel(
    const float* __restrict__ x, const float* __restrict__ rw,
    const float* __restrict__ rb, int2* __restrict__ experts,
    float2* __restrict__ wts, int T) {
  const int wave = threadIdx.x >> 6;
  const int lane = threadIdx.x & 63;
  const int t = blockIdx.x * 4 + wave;
  if (t >= T) return;
  const float* xr = x + (size_t)t * DD;
  float acc[NE] = {0.f, 0.f, 0.f, 0.f, 0.f, 0.f, 0.f, 0.f};
#pragma unroll
  for (int i = 0; i < 16; i++) {
    const int idx = lane + i * 64;
    const float xv = xr[idx];
    const float4* r4 = (const float4*)(rw + (size_t)idx * NE);
    float4 a = r4[0], b = r4[1];
    acc[0] += xv * a.x; acc[1] += xv * a.y; acc[2] += xv * a.z; acc[3] += xv * a.w;
    acc[4] += xv * b.x; acc[5] += xv * b.y; acc[6] += xv * b.z; acc[7] += xv * b.w;
  }
#pragma unroll
  for (int s = 1; s < 64; s <<= 1)
#pragma unroll
    for (int e = 0; e < NE; e++)
      acc[e] += __shfl_xor(acc[e], s);
  if (lane == 0) {
    float lg[NE];
#pragma unroll
    for (int e = 0; e < NE; e++) lg[e] = acc[e] + rb[e];
    // top-1 then top-2, ties -> lowest index (matches jax.lax.top_k)
    float l0 = lg[0]; int i0 = 0;
#pragma unroll
    for (int e = 1; e < NE; e++) if (lg[e] > l0) { l0 = lg[e]; i0 = e; }
    float l1 = -3.4e38f; int i1 = 0;
#pragma unroll
    for (int e = 0; e < NE; e++) {
      if (e == i0) continue;
      if (lg[e] > l1) { l1 = lg[e]; i1 = e; }
    }
    const float w0 = 1.f / (1.f + expf(l1 - l0));
    experts[t] = make_int2(i0, i1);
    wts[t] = make_float2(w0, 1.f - w0);
  }
}

// ---------------- count tokens per expert (block-aggregated atomics) ----------------
__global__ __launch_bounds__(256) void count_kernel(
    const int2* __restrict__ experts, int* __restrict__ counts, int T) {
  __shared__ int lc[NE];
  if (threadIdx.x < NE) lc[threadIdx.x] = 0;
  __syncthreads();
  const int t = blockIdx.x * 256 + threadIdx.x;
  if (t < T) {
    int2 e = experts[t];
    atomicAdd(&lc[e.x], 1);
    atomicAdd(&lc[e.y], 1);
  }
  __syncthreads();
  if (threadIdx.x < NE && lc[threadIdx.x] > 0)
    atomicAdd(&counts[threadIdx.x], lc[threadIdx.x]);
}

__global__ void offsets_kernel(const int* __restrict__ counts, int* __restrict__ offsets) {
  int s = 0;
  for (int e = 0; e < NE; e++) { offsets[e] = s; s += counts[e]; }
}

// ---------------- scatter token ids/weights into compact expert groups ----------------
__global__ __launch_bounds__(256) void scatter_kernel(
    const int2* __restrict__ experts, const float2* __restrict__ wts,
    const int* __restrict__ offsets, int* __restrict__ cursors,
    int* __restrict__ tok_id, float* __restrict__ tok_w, int T) {
  __shared__ int lc[NE], lb[NE];
  if (threadIdx.x < NE) lc[threadIdx.x] = 0;
  __syncthreads();
  const int t = blockIdx.x * 256 + threadIdx.x;
  int2 e = make_int2(0, 0);
  float2 w = make_float2(0.f, 0.f);
  int p0 = 0, p1 = 0;
  if (t < T) {
    e = experts[t]; w = wts[t];
    p0 = atomicAdd(&lc[e.x], 1);
    p1 = atomicAdd(&lc[e.y], 1);
  }
  __syncthreads();
  if (threadIdx.x < NE) lb[threadIdx.x] = atomicAdd(&cursors[threadIdx.x], lc[threadIdx.x]);
  __syncthreads();
  if (t < T) {
    const int s0 = offsets[e.x] + lb[e.x] + p0;
    tok_id[s0] = t; tok_w[s0] = w.x;
    const int s1 = offsets[e.y] + lb[e.y] + p1;
    tok_id[s1] = t; tok_w[s1] = w.y;
  }
}

// ---------------- weight transpose + fp32->bf16 convert ----------------
// Wgu: [e][nc][k], nc = ((n>>3)<<4) | (which<<3) | (n&7)  (gate/up interleaved per 16-col tile)
// Wd : [e][n][k]
__global__ __launch_bounds__(256) void convert_kernel(
    const float* __restrict__ wg, const float* __restrict__ wu,
    const float* __restrict__ wd, u16* __restrict__ Wgu, u16* __restrict__ Wd) {
  const int z = blockIdx.z;        // mat*8 + e
  const int mat = z >> 3;
  const int e = z & 7;
  const float* src = (mat == 0 ? wg : (mat == 1 ? wu : wd)) + (size_t)e * DD * DD;
  __shared__ float tile[64][65];
  const int k0 = blockIdx.y * 64, n0 = blockIdx.x * 64;
  const int tx = threadIdx.x & 63, ty = threadIdx.x >> 6;
#pragma unroll
  for (int i = 0; i < 16; i++) {
    const int kk = i * 4 + ty;
    tile[kk][tx] = src[(size_t)(k0 + kk) * DD + n0 + tx];
  }
  __syncthreads();
#pragma unroll
  for (int i = 0; i < 16; i++) {
    const int nn = i * 4 + ty;
    const int n = n0 + nn;
    const u16 h = f2bf(tile[tx][nn]);   // = src[k0+tx][n]
    if (mat == 2) {
      Wd[((size_t)e * DD + n) * DD + k0 + tx] = h;
    } else {
      const int nc = ((n >> 3) << 4) | (mat << 3) | (n & 7);
      Wgu[((size_t)e * 2048 + nc) * DD + k0 + tx] = h;
    }
  }
}

// ---------------- grouped GEMM 1: H = silu(x@Wg) * (x@Wu), bf16 MFMA ----------------
__global__ __launch_bounds__(256) void gateup_kernel(
    const float* __restrict__ x, const u16* __restrict__ Wgu,
    const int* __restrict__ tok_id, const int* __restrict__ offsets,
    const int* __restrict__ counts, u16* __restrict__ H) {
  const int e = blockIdx.z;
  const int cnt = counts[e];
  const int m0 = blockIdx.y * 128;
  if (m0 >= cnt) return;
  const int off = offsets[e];
  const int n0 = blockIdx.x * 128;

  __shared__ u16 As[128 * 32];
  __shared__ u16 Bs[128 * 32];

  const int t = threadIdx.x;
  const int lane = t & 63;
  const int wave = t >> 6;
  const int wm = (wave >> 1) * 64;
  const int wn = (wave & 1) * 64;
  const int r16 = lane & 15;
  const int quad = lane >> 4;

  // A-gather: thread covers 16 consecutive fp32 of one token row
  int arow = m0 + (t >> 1);
  if (arow > cnt - 1) arow = cnt - 1;
  const int tok = tok_id[off + arow];
  const int ah = (t & 1) * 16;
  const float* asrc = x + (size_t)tok * DD + ah;
  u16* adst = &As[(t >> 1) * 32 + ah];

  const u16* bsrc = Wgu + ((size_t)e * 2048 + n0) * DD;
  const int br0 = t >> 2;
  const int bkc = (t & 3) * 8;

  floatx4 acc[4][4];
#pragma unroll
  for (int i = 0; i < 4; i++)
#pragma unroll
    for (int j = 0; j < 4; j++)
      acc[i][j] = (floatx4){0.f, 0.f, 0.f, 0.f};

#pragma unroll 1
  for (int k0 = 0; k0 < DD; k0 += 32) {
    __syncthreads();
    GLOAD_LDS16(bsrc + (size_t)br0 * DD + k0 + bkc, &Bs[br0 * 32 + bkc]);
    GLOAD_LDS16(bsrc + (size_t)(br0 + 64) * DD + k0 + bkc, &Bs[(br0 + 64) * 32 + bkc]);
    const float4* ap = (const float4*)(asrc + k0);
    const float4 f0 = ap[0], f1 = ap[1], f2 = ap[2], f3 = ap[3];
    const uint4 h0 = make_uint4(pk2(f0.x, f0.y), pk2(f0.z, f0.w), pk2(f1.x, f1.y), pk2(f1.z, f1.w));
    const uint4 h1 = make_uint4(pk2(f2.x, f2.y), pk2(f2.z, f2.w), pk2(f3.x, f3.y), pk2(f3.z, f3.w));
    ((uint4*)adst)[0] = h0;
    ((uint4*)adst)[1] = h1;
    __syncthreads();
    short8 a[4], b[4];
#pragma unroll
    for (int i = 0; i < 4; i++)
      a[i] = *(const short8*)&As[(wm + i * 16 + r16) * 32 + quad * 8];
#pragma unroll
    for (int j = 0; j < 4; j++)
      b[j] = *(const short8*)&Bs[(wn + j * 16 + r16) * 32 + quad * 8];
#pragma unroll
    for (int i = 0; i < 4; i++)
#pragma unroll
      for (int j = 0; j < 4; j++)
        acc[i][j] = __builtin_amdgcn_mfma_f32_16x16x32_bf16(a[i], b[j], acc[i][j], 0, 0, 0);
  }

  // epilogue: pair gate (bit3=0) with up (bit3=1) via shfl_xor 8, silu, write bf16 H
#pragma unroll
  for (int i = 0; i < 4; i++) {
    const int mb = m0 + wm + i * 16 + quad * 4;
#pragma unroll
    for (int j = 0; j < 4; j++) {
      const int nc = n0 + wn + j * 16 + r16;
      const int ng = ((nc >> 4) << 3) | (nc & 7);
#pragma unroll
      for (int r = 0; r < 4; r++) {
        const float v = acc[i][j][r];
        const float pv = __shfl_xor(v, 8);
        const float g = (lane & 8) ? pv : v;
        const float u = (lane & 8) ? v : pv;
        const float hv = g * u / (1.f + __expf(-g));
        const int m = mb + r;
        if (!(lane & 8) && m < cnt)
          H[(size_t)(off + m) * DD + ng] = f2bf(hv);
      }
    }
  }
}

// ---------------- grouped GEMM 2: out[tok] += w * (H @ Wd) ----------------
__global__ __launch_bounds__(256) void down_kernel(
    const u16* __restrict__ H, const u16* __restrict__ Wd,
    const int* __restrict__ tok_id, const float* __restrict__ tok_w,
    const int* __restrict__ offsets, const int* __restrict__ counts,
    float* __restrict__ out, int TK2) {
  const int e = blockIdx.z;
  const int cnt = counts[e];
  const int m0 = blockIdx.y * 128;
  if (m0 >= cnt) return;
  const int off = offsets[e];
  const int n0 = blockIdx.x * 128;

  __shared__ u16 As[128 * 32];
  __shared__ u16 Bs[128 * 32];

  const int t = threadIdx.x;
  const int lane = t & 63;
  const int wave = t >> 6;
  const int wm = (wave >> 1) * 64;
  const int wn = (wave & 1) * 64;
  const int r16 = lane & 15;
  const int quad = lane >> 4;

  const int cr = t >> 2;
  const int ckc = (t & 3) * 8;
  int ar0 = off + m0 + cr;      if (ar0 > TK2 - 1) ar0 = TK2 - 1;
  int ar1 = off + m0 + cr + 64; if (ar1 > TK2 - 1) ar1 = TK2 - 1;
  const u16* bsrc = Wd + ((size_t)e * DD + n0) * DD;

  floatx4 acc[4][4];
#pragma unroll
  for (int i = 0; i < 4; i++)
#pragma unroll
    for (int j = 0; j < 4; j++)
      acc[i][j] = (floatx4){0.f, 0.f, 0.f, 0.f};

#pragma unroll 1
  for (int k0 = 0; k0 < DD; k0 += 32) {
    __syncthreads();
    GLOAD_LDS16(H + (size_t)ar0 * DD + k0 + ckc, &As[cr * 32 + ckc]);
    GLOAD_LDS16(H + (size_t)ar1 * DD + k0 + ckc, &As[(cr + 64) * 32 + ckc]);
    GLOAD_LDS16(bsrc + (size_t)cr * DD + k0 + ckc, &Bs[cr * 32 + ckc]);
    GLOAD_LDS16(bsrc + (size_t)(cr + 64) * DD + k0 + ckc, &Bs[(cr + 64) * 32 + ckc]);
    __syncthreads();
    short8 a[4], b[4];
#pragma unroll
    for (int i = 0; i < 4; i++)
      a[i] = *(const short8*)&As[(wm + i * 16 + r16) * 32 + quad * 8];
#pragma unroll
    for (int j = 0; j < 4; j++)
      b[j] = *(const short8*)&Bs[(wn + j * 16 + r16) * 32 + quad * 8];
#pragma unroll
    for (int i = 0; i < 4; i++)
#pragma unroll
      for (int j = 0; j < 4; j++)
        acc[i][j] = __builtin_amdgcn_mfma_f32_16x16x32_bf16(a[i], b[j], acc[i][j], 0, 0, 0);
  }

#pragma unroll
  for (int i = 0; i < 4; i++) {
    const int mb = m0 + wm + i * 16 + quad * 4;
#pragma unroll
    for (int r = 0; r < 4; r++) {
      const int m = mb + r;
      if (m < cnt) {
        const int slot = off + m;
        const int tk = tok_id[slot];
        const float w = tok_w[slot];
        float* orow = out + (size_t)tk * DD + n0 + wn + r16;
#pragma unroll
        for (int j = 0; j < 4; j++)
          atomicAdd(orow + j * 16, w * acc[i][j][r]);
      }
    }
  }
}

extern "C" void kernel_launch(void* const* d_in, const int* in_sizes, int n_in,
                              void* d_out, int out_size, void* d_ws, size_t ws_size,
                              hipStream_t stream) {
  const float* x  = (const float*)d_in[0];
  const float* rw = (const float*)d_in[1];
  const float* rb = (const float*)d_in[2];
  const float* wg = (const float*)d_in[3];
  const float* wu = (const float*)d_in[4];
  const float* wd = (const float*)d_in[5];
  float* out = (float*)d_out;
  const int T = in_sizes[0] / DD;       // 16384
  const int TK2 = 2 * T;

  // workspace carve
  char* p = (char*)d_ws;
  int* ctrl = (int*)p; p += 256;        // [0..7]=counts [8..15]=cursors [16..23]=offsets
  int2* experts = (int2*)p;  p += (size_t)T * 8;
  float2* wtsp  = (float2*)p; p += (size_t)T * 8;
  int* tok_id   = (int*)p;   p += (size_t)TK2 * 4;
  float* tok_w  = (float*)p; p += (size_t)TK2 * 4;
  u16* Wgu      = (u16*)p;   p += (size_t)NE * 2048 * DD * 2;
  u16* Wd       = (u16*)p;   p += (size_t)NE * DD * DD * 2;
  u16* H        = (u16*)p;   p += (size_t)TK2 * DD * 2;
  if ((size_t)(p - (char*)d_ws) > ws_size) return;  // insufficient scratch -> visible failure

  hipMemsetAsync(ctrl, 0, 256, stream);
  hipMemsetAsync(d_out, 0, (size_t)out_size * sizeof(float), stream);

  router_kernel<<<T / 4, 256, 0, stream>>>(x, rw, rb, experts, wtsp, T);
  count_kernel<<<T / 256, 256, 0, stream>>>(experts, ctrl, T);
  offsets_kernel<<<1, 1, 0, stream>>>(ctrl, ctrl + 16);
  scatter_kernel<<<T / 256, 256, 0, stream>>>(experts, wtsp, ctrl + 16, ctrl + 8, tok_id, tok_w, T);
  convert_kernel<<<dim3(16, 16, 24), 256, 0, stream>>>(wg, wu, wd, Wgu, Wd);
  gateup_kernel<<<dim3(16, (T + 127) / 128, NE), 256, 0, stream>>>(x, Wgu, tok_id, ctrl + 16, ctrl, H);
  down_kernel<<<dim3(8, (T + 127) / 128, NE), 256, 0, stream>>>(H, Wd, tok_id, tok_w, ctrl + 16, ctrl, out, TK2);
}

// Round 2
// 658.789 us; speedup vs baseline: 1.0242x; 1.0242x over previous
//
#include <hip/hip_runtime.h>
#include <hip/hip_bf16.h>
#include <cstdint>
#include <cstddef>

typedef unsigned short u16;
typedef unsigned int u32;
typedef __attribute__((ext_vector_type(8))) short short8;
typedef __attribute__((ext_vector_type(4))) float floatx4;

#define DD 1024
#define NE 8

// 16-byte async global->LDS copy (gfx950). LDS dest must be wave-uniform base + lane*16;
// global source address is per-lane (gather OK).
#define GLOAD_LDS16(G, L)                                               \
  __builtin_amdgcn_global_load_lds(                                     \
      (const __attribute__((address_space(1))) void*)(G),               \
      (__attribute__((address_space(3))) void*)(L), 16, 0, 0)

__device__ __forceinline__ u16 f2bf(float f) {
  union { __hip_bfloat16 h; u16 u; } cv;
  cv.h = __float2bfloat16(f);
  return cv.u;
}

__device__ __forceinline__ u32 pk2(float a, float b) {
  float2 t; t.x = a; t.y = b;
  union { __hip_bfloat162 h2; u32 u; } cv;
  cv.h2 = __float22bfloat162_rn(t);
  return cv.u;
}

// ---------------- router: fp32 logits, top-2, softmax weights; also emits x in bf16 ----------------
__global__ __launch_bounds__(256) void router_kernel(
    const float* __restrict__ x, const float* __restrict__ rw,
    const float* __restrict__ rb, int2* __restrict__ experts,
    float2* __restrict__ wts, u16* __restrict__ xbf, int T) {
  const int wave = threadIdx.x >> 6;
  const int lane = threadIdx.x & 63;
  const int t = blockIdx.x * 4 + wave;
  if (t >= T) return;
  const float* xr = x + (size_t)t * DD;
  float acc[NE] = {0.f, 0.f, 0.f, 0.f, 0.f, 0.f, 0.f, 0.f};
#pragma unroll
  for (int i = 0; i < 16; i++) {
    const int idx = lane + i * 64;
    const float xv = xr[idx];
    if (xbf) xbf[(size_t)t * DD + idx] = f2bf(xv);
    const float4* r4 = (const float4*)(rw + (size_t)idx * NE);
    float4 a = r4[0], b = r4[1];
    acc[0] += xv * a.x; acc[1] += xv * a.y; acc[2] += xv * a.z; acc[3] += xv * a.w;
    acc[4] += xv * b.x; acc[5] += xv * b.y; acc[6] += xv * b.z; acc[7] += xv * b.w;
  }
#pragma unroll
  for (int s = 1; s < 64; s <<= 1)
#pragma unroll
    for (int e = 0; e < NE; e++)
      acc[e] += __shfl_xor(acc[e], s);
  if (lane == 0) {
    float lg[NE];
#pragma unroll
    for (int e = 0; e < NE; e++) lg[e] = acc[e] + rb[e];
    // top-1 then top-2, ties -> lowest index (matches jax.lax.top_k)
    float l0 = lg[0]; int i0 = 0;
#pragma unroll
    for (int e = 1; e < NE; e++) if (lg[e] > l0) { l0 = lg[e]; i0 = e; }
    float l1 = -3.4e38f; int i1 = 0;
#pragma unroll
    for (int e = 0; e < NE; e++) {
      if (e == i0) continue;
      if (lg[e] > l1) { l1 = lg[e]; i1 = e; }
    }
    const float w0 = 1.f / (1.f + expf(l1 - l0));
    experts[t] = make_int2(i0, i1);
    wts[t] = make_float2(w0, 1.f - w0);
  }
}

// ---------------- count tokens per expert (block-aggregated atomics) ----------------
__global__ __launch_bounds__(256) void count_kernel(
    const int2* __restrict__ experts, int* __restrict__ counts, int T) {
  __shared__ int lc[NE];
  if (threadIdx.x < NE) lc[threadIdx.x] = 0;
  __syncthreads();
  const int t = blockIdx.x * 256 + threadIdx.x;
  if (t < T) {
    int2 e = experts[t];
    atomicAdd(&lc[e.x], 1);
    atomicAdd(&lc[e.y], 1);
  }
  __syncthreads();
  if (threadIdx.x < NE && lc[threadIdx.x] > 0)
    atomicAdd(&counts[threadIdx.x], lc[threadIdx.x]);
}

__global__ void offsets_kernel(const int* __restrict__ counts, int* __restrict__ offsets) {
  int s = 0;
  for (int e = 0; e < NE; e++) { offsets[e] = s; s += counts[e]; }
}

// ---------------- scatter token ids/weights into compact expert groups ----------------
__global__ __launch_bounds__(256) void scatter_kernel(
    const int2* __restrict__ experts, const float2* __restrict__ wts,
    const int* __restrict__ offsets, int* __restrict__ cursors,
    int* __restrict__ tok_id, float* __restrict__ tok_w, int T) {
  __shared__ int lc[NE], lb[NE];
  if (threadIdx.x < NE) lc[threadIdx.x] = 0;
  __syncthreads();
  const int t = blockIdx.x * 256 + threadIdx.x;
  int2 e = make_int2(0, 0);
  float2 w = make_float2(0.f, 0.f);
  int p0 = 0, p1 = 0;
  if (t < T) {
    e = experts[t]; w = wts[t];
    p0 = atomicAdd(&lc[e.x], 1);
    p1 = atomicAdd(&lc[e.y], 1);
  }
  __syncthreads();
  if (threadIdx.x < NE) lb[threadIdx.x] = atomicAdd(&cursors[threadIdx.x], lc[threadIdx.x]);
  __syncthreads();
  if (t < T) {
    const int s0 = offsets[e.x] + lb[e.x] + p0;
    tok_id[s0] = t; tok_w[s0] = w.x;
    const int s1 = offsets[e.y] + lb[e.y] + p1;
    tok_id[s1] = t; tok_w[s1] = w.y;
  }
}

// ---------------- weight transpose + fp32->bf16 convert ----------------
// Wgu: [e][nc][k], nc = ((n>>3)<<4) | (which<<3) | (n&7)  (gate/up interleaved per 16-col tile)
// Wd : [e][n][k]
__global__ __launch_bounds__(256) void convert_kernel(
    const float* __restrict__ wg, const float* __restrict__ wu,
    const float* __restrict__ wd, u16* __restrict__ Wgu, u16* __restrict__ Wd) {
  const int z = blockIdx.z;        // mat*8 + e
  const int mat = z >> 3;
  const int e = z & 7;
  const float* src = (mat == 0 ? wg : (mat == 1 ? wu : wd)) + (size_t)e * DD * DD;
  __shared__ float tile[64][65];
  const int k0 = blockIdx.y * 64, n0 = blockIdx.x * 64;
  const int tx = threadIdx.x & 63, ty = threadIdx.x >> 6;
#pragma unroll
  for (int i = 0; i < 16; i++) {
    const int kk = i * 4 + ty;
    tile[kk][tx] = src[(size_t)(k0 + kk) * DD + n0 + tx];
  }
  __syncthreads();
#pragma unroll
  for (int i = 0; i < 16; i++) {
    const int nn = i * 4 + ty;
    const int n = n0 + nn;
    const u16 h = f2bf(tile[tx][nn]);   // = src[k0+tx][n]
    if (mat == 2) {
      Wd[((size_t)e * DD + n) * DD + k0 + tx] = h;
    } else {
      const int nc = ((n >> 3) << 4) | (mat << 3) | (n & 7);
      Wgu[((size_t)e * 2048 + nc) * DD + k0 + tx] = h;
    }
  }
}

// ---------------- grouped GEMM 1 (bf16-A path): H = silu(x@Wg) * (x@Wu) ----------------
__global__ __launch_bounds__(256) void gateup_kernel_bf(
    const u16* __restrict__ xbf, const u16* __restrict__ Wgu,
    const int* __restrict__ tok_id, const int* __restrict__ offsets,
    const int* __restrict__ counts, u16* __restrict__ H) {
  const int e = blockIdx.z;
  const int cnt = counts[e];
  const int m0 = blockIdx.y * 128;
  if (m0 >= cnt) return;
  const int off = offsets[e];
  const int n0 = blockIdx.x * 128;

  __shared__ u16 As[128 * 32];
  __shared__ u16 Bs[128 * 32];

  const int t = threadIdx.x;
  const int lane = t & 63;
  const int wave = t >> 6;
  const int wm = (wave >> 1) * 64;
  const int wn = (wave & 1) * 64;
  const int r16 = lane & 15;
  const int quad = lane >> 4;

  const int cr = t >> 2;
  const int ckc = (t & 3) * 8;
  int r0 = m0 + cr;      if (r0 > cnt - 1) r0 = cnt - 1;
  int r1 = m0 + cr + 64; if (r1 > cnt - 1) r1 = cnt - 1;
  const int tok0 = tok_id[off + r0];
  const int tok1 = tok_id[off + r1];
  const u16* a0 = xbf + (size_t)tok0 * DD + ckc;
  const u16* a1 = xbf + (size_t)tok1 * DD + ckc;
  const u16* bsrc = Wgu + ((size_t)e * 2048 + n0) * DD + ckc;

  floatx4 acc[4][4];
#pragma unroll
  for (int i = 0; i < 4; i++)
#pragma unroll
    for (int j = 0; j < 4; j++)
      acc[i][j] = (floatx4){0.f, 0.f, 0.f, 0.f};

#pragma unroll 1
  for (int k0 = 0; k0 < DD; k0 += 32) {
    __syncthreads();
    GLOAD_LDS16(a0 + k0, &As[cr * 32 + ckc]);
    GLOAD_LDS16(a1 + k0, &As[(cr + 64) * 32 + ckc]);
    GLOAD_LDS16(bsrc + (size_t)cr * DD + k0, &Bs[cr * 32 + ckc]);
    GLOAD_LDS16(bsrc + (size_t)(cr + 64) * DD + k0, &Bs[(cr + 64) * 32 + ckc]);
    __syncthreads();
    short8 a[4], b[4];
#pragma unroll
    for (int i = 0; i < 4; i++)
      a[i] = *(const short8*)&As[(wm + i * 16 + r16) * 32 + quad * 8];
#pragma unroll
    for (int j = 0; j < 4; j++)
      b[j] = *(const short8*)&Bs[(wn + j * 16 + r16) * 32 + quad * 8];
#pragma unroll
    for (int i = 0; i < 4; i++)
#pragma unroll
      for (int j = 0; j < 4; j++)
        acc[i][j] = __builtin_amdgcn_mfma_f32_16x16x32_bf16(a[i], b[j], acc[i][j], 0, 0, 0);
  }

  // epilogue: pair gate (bit3=0) with up (bit3=1) via shfl_xor 8, silu, write bf16 H
#pragma unroll
  for (int i = 0; i < 4; i++) {
    const int mb = m0 + wm + i * 16 + quad * 4;
#pragma unroll
    for (int j = 0; j < 4; j++) {
      const int nc = n0 + wn + j * 16 + r16;
      const int ng = ((nc >> 4) << 3) | (nc & 7);
#pragma unroll
      for (int r = 0; r < 4; r++) {
        const float v = acc[i][j][r];
        const float pv = __shfl_xor(v, 8);
        const float g = (lane & 8) ? pv : v;
        const float u = (lane & 8) ? v : pv;
        const float hv = g * u / (1.f + __expf(-g));
        const int m = mb + r;
        if (!(lane & 8) && m < cnt)
          H[(size_t)(off + m) * DD + ng] = f2bf(hv);
      }
    }
  }
}

// ---------------- grouped GEMM 1 (fp32-A fallback, Round-1 path) ----------------
__global__ __launch_bounds__(256) void gateup_kernel_f32(
    const float* __restrict__ x, const u16* __restrict__ Wgu,
    const int* __restrict__ tok_id, const int* __restrict__ offsets,
    const int* __restrict__ counts, u16* __restrict__ H) {
  const int e = blockIdx.z;
  const int cnt = counts[e];
  const int m0 = blockIdx.y * 128;
  if (m0 >= cnt) return;
  const int off = offsets[e];
  const int n0 = blockIdx.x * 128;

  __shared__ u16 As[128 * 32];
  __shared__ u16 Bs[128 * 32];

  const int t = threadIdx.x;
  const int lane = t & 63;
  const int wave = t >> 6;
  const int wm = (wave >> 1) * 64;
  const int wn = (wave & 1) * 64;
  const int r16 = lane & 15;
  const int quad = lane >> 4;

  int arow = m0 + (t >> 1);
  if (arow > cnt - 1) arow = cnt - 1;
  const int tok = tok_id[off + arow];
  const int ah = (t & 1) * 16;
  const float* asrc = x + (size_t)tok * DD + ah;
  u16* adst = &As[(t >> 1) * 32 + ah];

  const u16* bsrc = Wgu + ((size_t)e * 2048 + n0) * DD;
  const int br0 = t >> 2;
  const int bkc = (t & 3) * 8;

  floatx4 acc[4][4];
#pragma unroll
  for (int i = 0; i < 4; i++)
#pragma unroll
    for (int j = 0; j < 4; j++)
      acc[i][j] = (floatx4){0.f, 0.f, 0.f, 0.f};

#pragma unroll 1
  for (int k0 = 0; k0 < DD; k0 += 32) {
    __syncthreads();
    GLOAD_LDS16(bsrc + (size_t)br0 * DD + k0 + bkc, &Bs[br0 * 32 + bkc]);
    GLOAD_LDS16(bsrc + (size_t)(br0 + 64) * DD + k0 + bkc, &Bs[(br0 + 64) * 32 + bkc]);
    const float4* ap = (const float4*)(asrc + k0);
    const float4 f0 = ap[0], f1 = ap[1], f2 = ap[2], f3 = ap[3];
    const uint4 h0 = make_uint4(pk2(f0.x, f0.y), pk2(f0.z, f0.w), pk2(f1.x, f1.y), pk2(f1.z, f1.w));
    const uint4 h1 = make_uint4(pk2(f2.x, f2.y), pk2(f2.z, f2.w), pk2(f3.x, f3.y), pk2(f3.z, f3.w));
    ((uint4*)adst)[0] = h0;
    ((uint4*)adst)[1] = h1;
    __syncthreads();
    short8 a[4], b[4];
#pragma unroll
    for (int i = 0; i < 4; i++)
      a[i] = *(const short8*)&As[(wm + i * 16 + r16) * 32 + quad * 8];
#pragma unroll
    for (int j = 0; j < 4; j++)
      b[j] = *(const short8*)&Bs[(wn + j * 16 + r16) * 32 + quad * 8];
#pragma unroll
    for (int i = 0; i < 4; i++)
#pragma unroll
      for (int j = 0; j < 4; j++)
        acc[i][j] = __builtin_amdgcn_mfma_f32_16x16x32_bf16(a[i], b[j], acc[i][j], 0, 0, 0);
  }

#pragma unroll
  for (int i = 0; i < 4; i++) {
    const int mb = m0 + wm + i * 16 + quad * 4;
#pragma unroll
    for (int j = 0; j < 4; j++) {
      const int nc = n0 + wn + j * 16 + r16;
      const int ng = ((nc >> 4) << 3) | (nc & 7);
#pragma unroll
      for (int r = 0; r < 4; r++) {
        const float v = acc[i][j][r];
        const float pv = __shfl_xor(v, 8);
        const float g = (lane & 8) ? pv : v;
        const float u = (lane & 8) ? v : pv;
        const float hv = g * u / (1.f + __expf(-g));
        const int m = mb + r;
        if (!(lane & 8) && m < cnt)
          H[(size_t)(off + m) * DD + ng] = f2bf(hv);
      }
    }
  }
}

// ---------------- grouped GEMM 2: out[tok] += w * (H @ Wd) ----------------
__global__ __launch_bounds__(256) void down_kernel(
    const u16* __restrict__ H, const u16* __restrict__ Wd,
    const int* __restrict__ tok_id, const float* __restrict__ tok_w,
    const int* __restrict__ offsets, const int* __restrict__ counts,
    float* __restrict__ out, int TK2) {
  const int e = blockIdx.z;
  const int cnt = counts[e];
  const int m0 = blockIdx.y * 128;
  if (m0 >= cnt) return;
  const int off = offsets[e];
  const int n0 = blockIdx.x * 128;

  __shared__ u16 As[128 * 32];
  __shared__ u16 Bs[128 * 32];

  const int t = threadIdx.x;
  const int lane = t & 63;
  const int wave = t >> 6;
  const int wm = (wave >> 1) * 64;
  const int wn = (wave & 1) * 64;
  const int r16 = lane & 15;
  const int quad = lane >> 4;

  const int cr = t >> 2;
  const int ckc = (t & 3) * 8;
  int ar0 = off + m0 + cr;      if (ar0 > TK2 - 1) ar0 = TK2 - 1;
  int ar1 = off + m0 + cr + 64; if (ar1 > TK2 - 1) ar1 = TK2 - 1;
  const u16* bsrc = Wd + ((size_t)e * DD + n0) * DD;

  floatx4 acc[4][4];
#pragma unroll
  for (int i = 0; i < 4; i++)
#pragma unroll
    for (int j = 0; j < 4; j++)
      acc[i][j] = (floatx4){0.f, 0.f, 0.f, 0.f};

#pragma unroll 1
  for (int k0 = 0; k0 < DD; k0 += 32) {
    __syncthreads();
    GLOAD_LDS16(H + (size_t)ar0 * DD + k0 + ckc, &As[cr * 32 + ckc]);
    GLOAD_LDS16(H + (size_t)ar1 * DD + k0 + ckc, &As[(cr + 64) * 32 + ckc]);
    GLOAD_LDS16(bsrc + (size_t)cr * DD + k0 + ckc, &Bs[cr * 32 + ckc]);
    GLOAD_LDS16(bsrc + (size_t)(cr + 64) * DD + k0 + ckc, &Bs[(cr + 64) * 32 + ckc]);
    __syncthreads();
    short8 a[4], b[4];
#pragma unroll
    for (int i = 0; i < 4; i++)
      a[i] = *(const short8*)&As[(wm + i * 16 + r16) * 32 + quad * 8];
#pragma unroll
    for (int j = 0; j < 4; j++)
      b[j] = *(const short8*)&Bs[(wn + j * 16 + r16) * 32 + quad * 8];
#pragma unroll
    for (int i = 0; i < 4; i++)
#pragma unroll
      for (int j = 0; j < 4; j++)
        acc[i][j] = __builtin_amdgcn_mfma_f32_16x16x32_bf16(a[i], b[j], acc[i][j], 0, 0, 0);
  }

#pragma unroll
  for (int i = 0; i < 4; i++) {
    const int mb = m0 + wm + i * 16 + quad * 4;
#pragma unroll
    for (int r = 0; r < 4; r++) {
      const int m = mb + r;
      if (m < cnt) {
        const int slot = off + m;
        const int tk = tok_id[slot];
        const float w = tok_w[slot];
        float* orow = out + (size_t)tk * DD + n0 + wn + r16;
#pragma unroll
        for (int j = 0; j < 4; j++)
          atomicAdd(orow + j * 16, w * acc[i][j][r]);
      }
    }
  }
}

extern "C" void kernel_launch(void* const* d_in, const int* in_sizes, int n_in,
                              void* d_out, int out_size, void* d_ws, size_t ws_size,
                              hipStream_t stream) {
  const float* x  = (const float*)d_in[0];
  const float* rw = (const float*)d_in[1];
  const float* rb = (const float*)d_in[2];
  const float* wg = (const float*)d_in[3];
  const float* wu = (const float*)d_in[4];
  const float* wd = (const float*)d_in[5];
  float* out = (float*)d_out;
  const int T = in_sizes[0] / DD;       // 16384
  const int TK2 = 2 * T;

  // workspace carve
  char* p = (char*)d_ws;
  int* ctrl = (int*)p; p += 256;        // [0..7]=counts [8..15]=cursors [16..23]=offsets
  int2* experts = (int2*)p;  p += (size_t)T * 8;
  float2* wtsp  = (float2*)p; p += (size_t)T * 8;
  int* tok_id   = (int*)p;   p += (size_t)TK2 * 4;
  float* tok_w  = (float*)p; p += (size_t)TK2 * 4;
  u16* Wgu      = (u16*)p;   p += (size_t)NE * 2048 * DD * 2;
  u16* Wd       = (u16*)p;   p += (size_t)NE * DD * DD * 2;
  u16* H        = (u16*)p;   p += (size_t)TK2 * DD * 2;
  const size_t base_need = (size_t)(p - (char*)d_ws);
  u16* xbf = (u16*)p;
  const size_t xbf_need = base_need + (size_t)T * DD * 2;
  const bool use_bf_a = (xbf_need <= ws_size);
  if (base_need > ws_size) return;      // insufficient scratch -> visible failure

  hipMemsetAsync(ctrl, 0, 256, stream);
  hipMemsetAsync(d_out, 0, (size_t)out_size * sizeof(float), stream);

  router_kernel<<<T / 4, 256, 0, stream>>>(x, rw, rb, experts, wtsp,
                                           use_bf_a ? xbf : (u16*)nullptr, T);
  count_kernel<<<T / 256, 256, 0, stream>>>(experts, ctrl, T);
  offsets_kernel<<<1, 1, 0, stream>>>(ctrl, ctrl + 16);
  scatter_kernel<<<T / 256, 256, 0, stream>>>(experts, wtsp, ctrl + 16, ctrl + 8, tok_id, tok_w, T);
  convert_kernel<<<dim3(16, 16, 24), 256, 0, stream>>>(wg, wu, wd, Wgu, Wd);
  if (use_bf_a) {
    gateup_kernel_bf<<<dim3(16, (T + 127) / 128, NE), 256, 0, stream>>>(
        xbf, Wgu, tok_id, ctrl + 16, ctrl, H);
  } else {
    gateup_kernel_f32<<<dim3(16, (T + 127) / 128, NE), 256, 0, stream>>>(
        x, Wgu, tok_id, ctrl + 16, ctrl, H);
  }
  down_kernel<<<dim3(8, (T + 127) / 128, NE), 256, 0, stream>>>(
      H, Wd, tok_id, tok_w, ctrl + 16, ctrl, out, TK2);
}

// Round 3
// 509.030 us; speedup vs baseline: 1.3255x; 1.2942x over previous
//
#include <hip/hip_runtime.h>
#include <hip/hip_bf16.h>
#include <cstdint>
#include <cstddef>

typedef unsigned short u16;
typedef unsigned int u32;
typedef __attribute__((ext_vector_type(8))) short short8;
typedef __attribute__((ext_vector_type(4))) float floatx4;

#define DD 1024
#define NE 8

// 16-byte async global->LDS copy (gfx950). LDS dest must be wave-uniform base + lane*16;
// global source address is per-lane (gather OK).
#define GLOAD_LDS16(G, L)                                               \
  __builtin_amdgcn_global_load_lds(                                     \
      (const __attribute__((address_space(1))) void*)(G),               \
      (__attribute__((address_space(3))) void*)(L), 16, 0, 0)

__device__ __forceinline__ u16 f2bf(float f) {
  union { __hip_bfloat16 h; u16 u; } cv;
  cv.h = __float2bfloat16(f);
  return cv.u;
}

__device__ __forceinline__ float2 bf2f2(u32 u) {
  union { u32 v; float f; } lo, hi;
  lo.v = u << 16; hi.v = u & 0xffff0000u;
  float2 r; r.x = lo.f; r.y = hi.f; return r;
}

// ---------------- router: fp32 logits, top-2, softmax weights; emits x in bf16 ----------------
__global__ __launch_bounds__(256) void router_kernel(
    const float* __restrict__ x, const float* __restrict__ rw,
    const float* __restrict__ rb, int2* __restrict__ experts,
    float2* __restrict__ wts, u16* __restrict__ xbf, int T) {
  const int wave = threadIdx.x >> 6;
  const int lane = threadIdx.x & 63;
  const int t = blockIdx.x * 4 + wave;
  if (t >= T) return;
  const float* xr = x + (size_t)t * DD;
  float acc[NE] = {0.f, 0.f, 0.f, 0.f, 0.f, 0.f, 0.f, 0.f};
#pragma unroll
  for (int i = 0; i < 16; i++) {
    const int idx = lane + i * 64;
    const float xv = xr[idx];
    xbf[(size_t)t * DD + idx] = f2bf(xv);
    const float4* r4 = (const float4*)(rw + (size_t)idx * NE);
    float4 a = r4[0], b = r4[1];
    acc[0] += xv * a.x; acc[1] += xv * a.y; acc[2] += xv * a.z; acc[3] += xv * a.w;
    acc[4] += xv * b.x; acc[5] += xv * b.y; acc[6] += xv * b.z; acc[7] += xv * b.w;
  }
#pragma unroll
  for (int s = 1; s < 64; s <<= 1)
#pragma unroll
    for (int e = 0; e < NE; e++)
      acc[e] += __shfl_xor(acc[e], s);
  if (lane == 0) {
    float lg[NE];
#pragma unroll
    for (int e = 0; e < NE; e++) lg[e] = acc[e] + rb[e];
    float l0 = lg[0]; int i0 = 0;
#pragma unroll
    for (int e = 1; e < NE; e++) if (lg[e] > l0) { l0 = lg[e]; i0 = e; }
    float l1 = -3.4e38f; int i1 = 0;
#pragma unroll
    for (int e = 0; e < NE; e++) {
      if (e == i0) continue;
      if (lg[e] > l1) { l1 = lg[e]; i1 = e; }
    }
    const float w0 = 1.f / (1.f + expf(l1 - l0));
    experts[t] = make_int2(i0, i1);
    wts[t] = make_float2(w0, 1.f - w0);
  }
}

// ---------------- count tokens per expert ----------------
__global__ __launch_bounds__(256) void count_kernel(
    const int2* __restrict__ experts, int* __restrict__ counts, int T) {
  __shared__ int lc[NE];
  if (threadIdx.x < NE) lc[threadIdx.x] = 0;
  __syncthreads();
  const int t = blockIdx.x * 256 + threadIdx.x;
  if (t < T) {
    int2 e = experts[t];
    atomicAdd(&lc[e.x], 1);
    atomicAdd(&lc[e.y], 1);
  }
  __syncthreads();
  if (threadIdx.x < NE && lc[threadIdx.x] > 0)
    atomicAdd(&counts[threadIdx.x], lc[threadIdx.x]);
}

__global__ void offsets_kernel(const int* __restrict__ counts, int* __restrict__ offsets) {
  int s = 0;
  for (int e = 0; e < NE; e++) { offsets[e] = s; s += counts[e]; }
}

// ---------------- scatter: compact expert groups + inverse map (slots per token) ----------------
__global__ __launch_bounds__(256) void scatter_kernel(
    const int2* __restrict__ experts, const int* __restrict__ offsets,
    int* __restrict__ cursors, int* __restrict__ tok_id,
    int2* __restrict__ slots, int T) {
  __shared__ int lc[NE], lb[NE];
  if (threadIdx.x < NE) lc[threadIdx.x] = 0;
  __syncthreads();
  const int t = blockIdx.x * 256 + threadIdx.x;
  int2 e = make_int2(0, 0);
  int p0 = 0, p1 = 0;
  if (t < T) {
    e = experts[t];
    p0 = atomicAdd(&lc[e.x], 1);
    p1 = atomicAdd(&lc[e.y], 1);
  }
  __syncthreads();
  if (threadIdx.x < NE) lb[threadIdx.x] = atomicAdd(&cursors[threadIdx.x], lc[threadIdx.x]);
  __syncthreads();
  if (t < T) {
    const int s0 = offsets[e.x] + lb[e.x] + p0;
    const int s1 = offsets[e.y] + lb[e.y] + p1;
    tok_id[s0] = t;
    tok_id[s1] = t;
    slots[t] = make_int2(s0, s1);
  }
}

// ---------------- weight transpose + fp32->bf16 convert ----------------
// Wgu: [e][nc][k], nc = ((n>>3)<<4) | (which<<3) | (n&7); Wd: [e][n][k]
__global__ __launch_bounds__(256) void convert_kernel(
    const float* __restrict__ wg, const float* __restrict__ wu,
    const float* __restrict__ wd, u16* __restrict__ Wgu, u16* __restrict__ Wd) {
  const int z = blockIdx.z;        // mat*8 + e
  const int mat = z >> 3;
  const int e = z & 7;
  const float* src = (mat == 0 ? wg : (mat == 1 ? wu : wd)) + (size_t)e * DD * DD;
  __shared__ float tile[64][65];
  const int k0 = blockIdx.y * 64, n0 = blockIdx.x * 64;
  const int tx = threadIdx.x & 63, ty = threadIdx.x >> 6;
#pragma unroll
  for (int i = 0; i < 16; i++) {
    const int kk = i * 4 + ty;
    tile[kk][tx] = src[(size_t)(k0 + kk) * DD + n0 + tx];
  }
  __syncthreads();
#pragma unroll
  for (int i = 0; i < 16; i++) {
    const int nn = i * 4 + ty;
    const int n = n0 + nn;
    const u16 h = f2bf(tile[tx][nn]);   // = src[k0+tx][n]
    if (mat == 2) {
      Wd[((size_t)e * DD + n) * DD + k0 + tx] = h;
    } else {
      const int nc = ((n >> 3) << 4) | (mat << 3) | (n & 7);
      Wgu[((size_t)e * 2048 + nc) * DD + k0 + tx] = h;
    }
  }
}

// ---------------- grouped GEMM 1: H = silu(x@Wg)*(x@Wu), BK=64, swizzled LDS ----------------
__global__ __launch_bounds__(256) void gateup_kernel(
    const u16* __restrict__ xbf, const u16* __restrict__ Wgu,
    const int* __restrict__ tok_id, const int* __restrict__ offsets,
    const int* __restrict__ counts, u16* __restrict__ H) {
  const int e = blockIdx.z;
  const int cnt = counts[e];
  const int m0 = blockIdx.y * 128;
  if (m0 >= cnt) return;
  const int off = offsets[e];
  const int n0 = blockIdx.x * 128;

  __shared__ u16 As[128 * 64];
  __shared__ u16 Bs[128 * 64];

  const int t = threadIdx.x;
  const int lane = t & 63;
  const int wave = t >> 6;
  const int wm = (wave >> 1) * 64;
  const int wn = (wave & 1) * 64;
  const int r16 = lane & 15;
  const int quad = lane >> 4;

  // DMA mapping: issue i covers rows i*32 + (t>>3); lane supplies chunk position t&7,
  // whose LOGICAL k-chunk is (t&7) ^ (row&7)  (XOR swizzle; dest stays lane-linear).
  const int drow = t >> 3;
  const int dpos = t & 7;
  const u16* srcA[4];
  const u16* srcB[4];
  const u16* bbase = Wgu + ((size_t)e * 2048 + n0) * DD;
#pragma unroll
  for (int i = 0; i < 4; i++) {
    const int row = drow + i * 32;
    int r = m0 + row; if (r > cnt - 1) r = cnt - 1;
    const int tok = tok_id[off + r];
    const int ka = (dpos ^ (row & 7)) * 8;
    srcA[i] = xbf + (size_t)tok * DD + ka;
    srcB[i] = bbase + (size_t)row * DD + ka;
  }

  floatx4 acc[4][4];
#pragma unroll
  for (int i = 0; i < 4; i++)
#pragma unroll
    for (int j = 0; j < 4; j++)
      acc[i][j] = (floatx4){0.f, 0.f, 0.f, 0.f};

#pragma unroll 1
  for (int k0 = 0; k0 < DD; k0 += 64) {
    __syncthreads();
#pragma unroll
    for (int i = 0; i < 4; i++) {
      GLOAD_LDS16(srcA[i] + k0, &As[t * 8 + i * 2048]);
      GLOAD_LDS16(srcB[i] + k0, &Bs[t * 8 + i * 2048]);
    }
    __syncthreads();
#pragma unroll
    for (int s = 0; s < 2; s++) {
      short8 a[4], b[4];
#pragma unroll
      for (int i = 0; i < 4; i++)
        a[i] = *(const short8*)&As[(wm + i * 16 + r16) * 64 + (((s << 2) + quad) ^ (r16 & 7)) * 8];
#pragma unroll
      for (int j = 0; j < 4; j++)
        b[j] = *(const short8*)&Bs[(wn + j * 16 + r16) * 64 + (((s << 2) + quad) ^ (r16 & 7)) * 8];
#pragma unroll
      for (int i = 0; i < 4; i++)
#pragma unroll
        for (int j = 0; j < 4; j++)
          acc[i][j] = __builtin_amdgcn_mfma_f32_16x16x32_bf16(a[i], b[j], acc[i][j], 0, 0, 0);
    }
  }

  // epilogue: pair gate (bit3=0) with up (bit3=1) via shfl_xor 8, silu, write bf16 H
#pragma unroll
  for (int i = 0; i < 4; i++) {
    const int mb = m0 + wm + i * 16 + quad * 4;
#pragma unroll
    for (int j = 0; j < 4; j++) {
      const int nc = n0 + wn + j * 16 + r16;
      const int ng = ((nc >> 4) << 3) | (nc & 7);
#pragma unroll
      for (int r = 0; r < 4; r++) {
        const float v = acc[i][j][r];
        const float pv = __shfl_xor(v, 8);
        const float g = (lane & 8) ? pv : v;
        const float u = (lane & 8) ? v : pv;
        const float hv = g * u / (1.f + __expf(-g));
        const int m = mb + r;
        if (!(lane & 8) && m < cnt)
          H[(size_t)(off + m) * DD + ng] = f2bf(hv);
      }
    }
  }
}

// ---------------- grouped GEMM 2: Y[slot] = H[slot] @ Wd  (bf16 stores, no atomics) ----------------
__global__ __launch_bounds__(256) void down_kernel(
    const u16* __restrict__ H, const u16* __restrict__ Wd,
    const int* __restrict__ counts, const int* __restrict__ offsets,
    u16* __restrict__ Y, int TK2) {
  const int e = blockIdx.z;
  const int cnt = counts[e];
  const int m0 = blockIdx.y * 128;
  if (m0 >= cnt) return;
  const int off = offsets[e];
  const int n0 = blockIdx.x * 128;

  __shared__ u16 As[128 * 64];
  __shared__ u16 Bs[128 * 64];

  const int t = threadIdx.x;
  const int lane = t & 63;
  const int wave = t >> 6;
  const int wm = (wave >> 1) * 64;
  const int wn = (wave & 1) * 64;
  const int r16 = lane & 15;
  const int quad = lane >> 4;

  const int drow = t >> 3;
  const int dpos = t & 7;
  const u16* srcA[4];
  const u16* srcB[4];
  const u16* bbase = Wd + ((size_t)e * DD + n0) * DD;
#pragma unroll
  for (int i = 0; i < 4; i++) {
    const int row = drow + i * 32;
    int r = off + m0 + row; if (r > TK2 - 1) r = TK2 - 1;
    const int ka = (dpos ^ (row & 7)) * 8;
    srcA[i] = H + (size_t)r * DD + ka;
    srcB[i] = bbase + (size_t)row * DD + ka;
  }

  floatx4 acc[4][4];
#pragma unroll
  for (int i = 0; i < 4; i++)
#pragma unroll
    for (int j = 0; j < 4; j++)
      acc[i][j] = (floatx4){0.f, 0.f, 0.f, 0.f};

#pragma unroll 1
  for (int k0 = 0; k0 < DD; k0 += 64) {
    __syncthreads();
#pragma unroll
    for (int i = 0; i < 4; i++) {
      GLOAD_LDS16(srcA[i] + k0, &As[t * 8 + i * 2048]);
      GLOAD_LDS16(srcB[i] + k0, &Bs[t * 8 + i * 2048]);
    }
    __syncthreads();
#pragma unroll
    for (int s = 0; s < 2; s++) {
      short8 a[4], b[4];
#pragma unroll
      for (int i = 0; i < 4; i++)
        a[i] = *(const short8*)&As[(wm + i * 16 + r16) * 64 + (((s << 2) + quad) ^ (r16 & 7)) * 8];
#pragma unroll
      for (int j = 0; j < 4; j++)
        b[j] = *(const short8*)&Bs[(wn + j * 16 + r16) * 64 + (((s << 2) + quad) ^ (r16 & 7)) * 8];
#pragma unroll
      for (int i = 0; i < 4; i++)
#pragma unroll
        for (int j = 0; j < 4; j++)
          acc[i][j] = __builtin_amdgcn_mfma_f32_16x16x32_bf16(a[i], b[j], acc[i][j], 0, 0, 0);
    }
  }

#pragma unroll
  for (int i = 0; i < 4; i++) {
    const int mb = m0 + wm + i * 16 + quad * 4;
#pragma unroll
    for (int r = 0; r < 4; r++) {
      const int m = mb + r;
      if (m < cnt) {
        u16* yrow = Y + (size_t)(off + m) * DD + n0 + wn + r16;
#pragma unroll
        for (int j = 0; j < 4; j++)
          yrow[j * 16] = f2bf(acc[i][j][r]);
      }
    }
  }
}

// ---------------- combine: out[t] = w0*Y[s0] + w1*Y[s1] ----------------
__global__ __launch_bounds__(256) void combine_kernel(
    const u16* __restrict__ Y, const int2* __restrict__ slots,
    const float2* __restrict__ wts, float* __restrict__ out, int T) {
  const int wave = threadIdx.x >> 6;
  const int lane = threadIdx.x & 63;
  const int t = blockIdx.x * 4 + wave;
  if (t >= T) return;
  const int2 s = slots[t];
  const float2 w = wts[t];
  const uint4* y0 = (const uint4*)(Y + (size_t)s.x * DD);
  const uint4* y1 = (const uint4*)(Y + (size_t)s.y * DD);
  float4* o = (float4*)(out + (size_t)t * DD);
#pragma unroll
  for (int c = 0; c < 2; c++) {
    const int idx = lane + c * 64;          // 128 uint4 per row (8 bf16 each)
    const uint4 a = y0[idx];
    const uint4 b = y1[idx];
    const u32 au[4] = {a.x, a.y, a.z, a.w};
    const u32 bu[4] = {b.x, b.y, b.z, b.w};
    float4 r[2];
#pragma unroll
    for (int q = 0; q < 4; q++) {
      const float2 fa = bf2f2(au[q]);
      const float2 fb = bf2f2(bu[q]);
      ((float*)r)[q * 2]     = w.x * fa.x + w.y * fb.x;
      ((float*)r)[q * 2 + 1] = w.x * fa.y + w.y * fb.y;
    }
    o[idx * 2]     = r[0];
    o[idx * 2 + 1] = r[1];
  }
}

extern "C" void kernel_launch(void* const* d_in, const int* in_sizes, int n_in,
                              void* d_out, int out_size, void* d_ws, size_t ws_size,
                              hipStream_t stream) {
  const float* x  = (const float*)d_in[0];
  const float* rw = (const float*)d_in[1];
  const float* rb = (const float*)d_in[2];
  const float* wg = (const float*)d_in[3];
  const float* wu = (const float*)d_in[4];
  const float* wd = (const float*)d_in[5];
  float* out = (float*)d_out;
  const int T = in_sizes[0] / DD;       // 16384
  const int TK2 = 2 * T;

  // workspace carve. Y (64MB) aliases [Wgu(32MB) xbf(32MB)], which are dead after gateup.
  char* p = (char*)d_ws;
  int* ctrl = (int*)p; p += 256;        // [0..7]=counts [8..15]=cursors [16..23]=offsets
  int2* experts = (int2*)p;  p += (size_t)T * 8;
  float2* wtsp  = (float2*)p; p += (size_t)T * 8;
  int* tok_id   = (int*)p;   p += (size_t)TK2 * 4;
  int2* slots   = (int2*)p;  p += (size_t)T * 8;
  u16* Wd       = (u16*)p;   p += (size_t)NE * DD * DD * 2;
  u16* H        = (u16*)p;   p += (size_t)TK2 * DD * 2;
  u16* Wgu      = (u16*)p;   // 32 MB
  u16* xbf      = (u16*)(p + (size_t)NE * 2048 * DD * 2);  // 32 MB
  u16* Y        = (u16*)p;   // 64 MB, aliases Wgu+xbf
  p += (size_t)TK2 * DD * 2;
  if ((size_t)(p - (char*)d_ws) > ws_size) return;  // insufficient scratch -> visible failure

  hipMemsetAsync(ctrl, 0, 256, stream);

  router_kernel<<<T / 4, 256, 0, stream>>>(x, rw, rb, experts, wtsp, xbf, T);
  count_kernel<<<T / 256, 256, 0, stream>>>(experts, ctrl, T);
  offsets_kernel<<<1, 1, 0, stream>>>(ctrl, ctrl + 16);
  scatter_kernel<<<T / 256, 256, 0, stream>>>(experts, ctrl + 16, ctrl + 8, tok_id, slots, T);
  convert_kernel<<<dim3(16, 16, 24), 256, 0, stream>>>(wg, wu, wd, Wgu, Wd);
  gateup_kernel<<<dim3(16, (T + 127) / 128, NE), 256, 0, stream>>>(
      xbf, Wgu, tok_id, ctrl + 16, ctrl, H);
  down_kernel<<<dim3(8, (T + 127) / 128, NE), 256, 0, stream>>>(
      H, Wd, ctrl, ctrl + 16, Y, TK2);
  combine_kernel<<<T / 4, 256, 0, stream>>>(Y, slots, wtsp, out, T);
}